// Round 10
// baseline (2274.120 us; speedup 1.0000x reference)
//
#include <hip/hip_runtime.h>

typedef unsigned short u16;
typedef unsigned int u32;
typedef unsigned long long u64;

#define NBLK 256

__device__ __forceinline__ float b2f(u16 u) {
    u32 i = ((u32)u) << 16;
    return __builtin_bit_cast(float, i);
}
__device__ __forceinline__ u16 f2b(float f) {
    u32 b = __builtin_bit_cast(u32, f);
    b += 0x7FFFu + ((b >> 16) & 1u);   // RNE
    return (u16)(b >> 16);
}
__device__ __forceinline__ float sigm(float x) {
    return 1.f / (1.f + __expf(-x));
}
__device__ __forceinline__ float tanh_fast(float x) {
    float a = fabsf(x);
    float e = __expf(-2.f * a);            // in (0,1], never inf
    float r = (1.f - e) / (1.f + e);
    return copysignf(r, x);
}

// ---------------------------------------------------------------------------
// Single persistent kernel: LSTM chain with the input-projection (Xproj)
// FUSED into each step's poll shadow. 256 WGs x 512 thr, 1 WG/CU.
//  - Whh rows in fp32 registers (w[4][32]); h exchange bf16-packed,
//    data-is-the-flag (poll hseqB[t-1], single copy).
//  - Block wg's 32 Wih rows (in & out phases) staged in LDS (128KB);
//    step t computes Xp[t+4] into an 8-deep LDS ring AFTER the tail,
//    while the next step's h is still in flight (free shadow work).
//  - x rows pipelined: token for t+6 and embed row for t+5 loaded each
//    step AFTER the poll (in-order VMEM: nothing issued pre-poll).
// ---------------------------------------------------------------------------
__global__ void __launch_bounds__(512, 1)
rnn_coop(const float* __restrict__ WhhA, const float* __restrict__ WhhB,
         const float* __restrict__ pWih, const float* __restrict__ pWhh,
         const float* __restrict__ pB,
         const float* __restrict__ inWih, const float* __restrict__ outWih,
         const float* __restrict__ in_b, const float* __restrict__ out_b,
         const float* __restrict__ embed, const float* __restrict__ eos,
         const int* __restrict__ in_seq, const int* __restrict__ out_seq,
         u32* __restrict__ hseqB, float* __restrict__ out)
{
    __shared__ __align__(16) float wihA[32 * 512];   // 64KB in_Wih slice
    __shared__ __align__(16) float wihB[32 * 512];   // 64KB out_Wih slice
    __shared__ __align__(16) float hs[2048];         // 8KB staged fp32 h
    __shared__ __align__(16) float xbuf[2][512];     // 4KB x double buffer
    __shared__ float ring[8][32];                    // Xp ring (lookahead 4)
    __shared__ float biasA[32], biasB[32], gsum[32];

    const int wg = blockIdx.x;
    const int tid = threadIdx.x;
    const int lane = tid & 63;
    const int wv = tid >> 6;

    float w[4][32];        // fp32 Whh slice: rows rl=4*wv+rr, 32 cols/lane
    float c_reg = 0.f;     // valid on lanes 0-7 of wave 0
    float xp2 = 0.f;       // phase-2 gate input (pB), wave0 lanes 0-31

    // ---- bootstrap: stage Wih slices + biases ----
    for (int idx = tid; idx < 4096; idx += 512) {
        int m = idx >> 7, c4 = (idx & 127) << 2;     // m = g*8+j
        size_t grow = (size_t)(((m >> 3) << 11) + (wg << 3) + (m & 7)) * 512;
        *(float4*)&wihA[m * 512 + c4] = *(const float4*)&inWih[grow + c4];
        *(float4*)&wihB[m * 512 + c4] = *(const float4*)&outWih[grow + c4];
    }
    if (tid < 32) {
        int gofs = ((tid >> 3) << 11) + (wg << 3) + (tid & 7);
        biasA[tid] = in_b[gofs];
        biasB[tid] = out_b[gofs];
        gsum[tid] = 0.f;
    }
    __syncthreads();

    // ---- bootstrap: ring[0..3] = Xp[0..3]; leave xbuf[0] = x_4 ----
    for (int tt = 0; tt < 4; ++tt) {
        xbuf[0][tid] = embed[(size_t)in_seq[tt] * 512 + tid];
        __syncthreads();
        float a0 = 0.f, a1 = 0.f, a2 = 0.f, a3 = 0.f;
        const int m0 = wv << 2;
#pragma unroll
        for (int q = 0; q < 2; ++q) {
            float4 xv = *(const float4*)&xbuf[0][(q << 8) + (lane << 2)];
            float4 w0 = *(const float4*)&wihA[(m0 + 0) * 512 + (q << 8) + (lane << 2)];
            float4 w1 = *(const float4*)&wihA[(m0 + 1) * 512 + (q << 8) + (lane << 2)];
            float4 w2 = *(const float4*)&wihA[(m0 + 2) * 512 + (q << 8) + (lane << 2)];
            float4 w3 = *(const float4*)&wihA[(m0 + 3) * 512 + (q << 8) + (lane << 2)];
            a0 = fmaf(w0.x, xv.x, fmaf(w0.y, xv.y, fmaf(w0.z, xv.z, fmaf(w0.w, xv.w, a0))));
            a1 = fmaf(w1.x, xv.x, fmaf(w1.y, xv.y, fmaf(w1.z, xv.z, fmaf(w1.w, xv.w, a1))));
            a2 = fmaf(w2.x, xv.x, fmaf(w2.y, xv.y, fmaf(w2.z, xv.z, fmaf(w2.w, xv.w, a2))));
            a3 = fmaf(w3.x, xv.x, fmaf(w3.y, xv.y, fmaf(w3.z, xv.z, fmaf(w3.w, xv.w, a3))));
        }
#pragma unroll
        for (int off = 32; off > 0; off >>= 1) {
            a0 += __shfl_xor(a0, off, 64);
            a1 += __shfl_xor(a1, off, 64);
            a2 += __shfl_xor(a2, off, 64);
            a3 += __shfl_xor(a3, off, 64);
        }
        if (lane == 0) {
            ring[tt][m0]     = a0 + biasA[m0];
            ring[tt][m0 + 1] = a1 + biasA[m0 + 1];
            ring[tt][m0 + 2] = a2 + biasA[m0 + 2];
            ring[tt][m0 + 3] = a3 + biasA[m0 + 3];
        }
        __syncthreads();
    }
    xbuf[0][tid] = embed[(size_t)in_seq[4] * 512 + tid];
    int tok_cur = in_seq[5];
    __syncthreads();

    for (int t = 0; t < 524; ++t) {
        const int phase = (t < 257) ? 0 : (t < 514) ? 1 : 2;

        if (t == 0 || t == 257 || t == 514) {
            if (phase < 2) {
                const float* Ws = phase ? WhhB : WhhA;
#pragma unroll
                for (int rr = 0; rr < 4; ++rr) {
                    int rl = (wv << 2) + rr;
                    const float* Wr = Ws + (size_t)(((rl >> 3) << 11) + (wg << 3) + (rl & 7)) * 2048;
#pragma unroll
                    for (int q = 0; q < 8; ++q)
                        *(float4*)&w[rr][q * 4] = *(const float4*)&Wr[(q << 8) + (lane << 2)];
                }
            } else {
#pragma unroll
                for (int rr = 0; rr < 4; ++rr) {
                    int rl = (wv << 2) + rr;
                    size_t off = (size_t)(((rl >> 3) << 11) + (wg << 3) + (rl & 7)) * 2048;
#pragma unroll
                    for (int q = 0; q < 8; ++q) {
                        float4 a = *(const float4*)&pWih[off + (q << 8) + (lane << 2)];
                        float4 b = *(const float4*)&pWhh[off + (q << 8) + (lane << 2)];
                        float4 s;
                        s.x = a.x + b.x; s.y = a.y + b.y;
                        s.z = a.z + b.z; s.w = a.w + b.w;
                        *(float4*)&w[rr][q * 4] = s;
                    }
                }
                if (wv == 0 && lane < 32)
                    xp2 = pB[((lane >> 3) << 11) + (wg << 3) + (lane & 7)];
            }
        }

        if (t > 0) {
            // poll own u64 (4 bf16) of hseqB[t-1]; sentinel 0xFFFF per u16.
            const u64* src = (const u64*)hseqB + (size_t)(t - 1) * 512 + tid;
            u64 a = __hip_atomic_load(src, __ATOMIC_RELAXED, __HIP_MEMORY_SCOPE_AGENT);
            while ((u16)a == 0xFFFFu || (u16)(a >> 16) == 0xFFFFu ||
                   (u16)(a >> 32) == 0xFFFFu || (u16)(a >> 48) == 0xFFFFu)
                a = __hip_atomic_load(src, __ATOMIC_RELAXED, __HIP_MEMORY_SCOPE_AGENT);
            float4 hv;
            hv.x = b2f((u16)a);         hv.y = b2f((u16)(a >> 16));
            hv.z = b2f((u16)(a >> 32)); hv.w = b2f((u16)(a >> 48));
            *(float4*)&hs[tid << 2] = hv;       // 16B/lane, conflict-free
        }
        __syncthreads();

        // x pipeline loads: AFTER the poll (in-order VMEM), consumed late.
        const int idx1 = t + 5, idx2 = t + 6;
        int tok_nxt = -2;
        float xnext = 0.f;
        if (idx2 <= 513)
            tok_nxt = (idx2 < 257) ? ((idx2 < 256) ? in_seq[idx2] : -1)
                                   : ((idx2 < 513) ? out_seq[idx2 - 257] : -1);
        if (idx1 <= 513)
            xnext = (tok_cur < 0) ? eos[tid] : embed[(size_t)tok_cur * 512 + tid];

        if (t > 0) {
            float a0 = 0.f, a1 = 0.f, a2 = 0.f, a3 = 0.f;
#pragma unroll
            for (int q = 0; q < 8; ++q) {
                float4 hv = *(const float4*)&hs[(q << 8) + (lane << 2)];
#pragma unroll
                for (int j = 0; j < 4; ++j) {
                    float h = ((const float*)&hv)[j];
                    a0 = fmaf(w[0][q * 4 + j], h, a0);
                    a1 = fmaf(w[1][q * 4 + j], h, a1);
                    a2 = fmaf(w[2][q * 4 + j], h, a2);
                    a3 = fmaf(w[3][q * 4 + j], h, a3);
                }
            }
#pragma unroll
            for (int off = 32; off > 0; off >>= 1) {
                a0 += __shfl_xor(a0, off, 64);
                a1 += __shfl_xor(a1, off, 64);
                a2 += __shfl_xor(a2, off, 64);
                a3 += __shfl_xor(a3, off, 64);
            }
            if (lane == 0) {
                const int rl = wv << 2;
                gsum[rl]     = a0;
                gsum[rl + 1] = a1;
                gsum[rl + 2] = a2;
                gsum[rl + 3] = a3;
            }
        }
        __syncthreads();

        if (wv == 0) {
            float xpv = (phase < 2) ? ring[t & 7][lane & 31] : xp2;
            float tot = xpv + gsum[lane & 31];
            float act = ((lane >> 3) == 2) ? tanh_fast(tot) : sigm(tot);
            const int j = lane & 7;
            float fi = __shfl(act, j, 64);        // gate i
            float ff = __shfl(act, 8 + j, 64);    // gate f
            float fg = __shfl(act, 16 + j, 64);   // gate g~
            float fo = __shfl(act, 24 + j, 64);   // gate o
            c_reg = ff * c_reg + fi * fg;
            float h2 = fo * tanh_fast(c_reg);
            u32 hb = (u32)f2b(h2);
            u32 lo = (u32)__shfl((int)hb, (lane & 3) * 2, 64);
            u32 hi = (u32)__shfl((int)hb, (lane & 3) * 2 + 1, 64);
            if (lane < 4)
                __hip_atomic_store(&hseqB[(size_t)t * 1024 + (wg << 2) + lane],
                                   (hi << 16) | lo,
                                   __ATOMIC_RELAXED, __HIP_MEMORY_SCOPE_AGENT);
            if (phase == 2 && lane < 8)
                out[(size_t)(t - 514) * 2048 + (wg << 3) + lane] = h2;
        }

        // ---- shadow work: Xp[t+4] into the ring (all 8 waves, while the
        //      next step's h is still in flight cross-chip) ----
        const int tt = t + 4;
        if (tt <= 513) {
            const bool inph = tt < 257;
            const float* wih = inph ? wihA : wihB;
            const float* bl  = inph ? biasA : biasB;
            const float* xb  = xbuf[tt & 1];
            float a0 = 0.f, a1 = 0.f, a2 = 0.f, a3 = 0.f;
            const int m0 = wv << 2;
#pragma unroll
            for (int q = 0; q < 2; ++q) {
                float4 xv = *(const float4*)&xb[(q << 8) + (lane << 2)];
                float4 w0 = *(const float4*)&wih[(m0 + 0) * 512 + (q << 8) + (lane << 2)];
                float4 w1 = *(const float4*)&wih[(m0 + 1) * 512 + (q << 8) + (lane << 2)];
                float4 w2 = *(const float4*)&wih[(m0 + 2) * 512 + (q << 8) + (lane << 2)];
                float4 w3 = *(const float4*)&wih[(m0 + 3) * 512 + (q << 8) + (lane << 2)];
                a0 = fmaf(w0.x, xv.x, fmaf(w0.y, xv.y, fmaf(w0.z, xv.z, fmaf(w0.w, xv.w, a0))));
                a1 = fmaf(w1.x, xv.x, fmaf(w1.y, xv.y, fmaf(w1.z, xv.z, fmaf(w1.w, xv.w, a1))));
                a2 = fmaf(w2.x, xv.x, fmaf(w2.y, xv.y, fmaf(w2.z, xv.z, fmaf(w2.w, xv.w, a2))));
                a3 = fmaf(w3.x, xv.x, fmaf(w3.y, xv.y, fmaf(w3.z, xv.z, fmaf(w3.w, xv.w, a3))));
            }
#pragma unroll
            for (int off = 32; off > 0; off >>= 1) {
                a0 += __shfl_xor(a0, off, 64);
                a1 += __shfl_xor(a1, off, 64);
                a2 += __shfl_xor(a2, off, 64);
                a3 += __shfl_xor(a3, off, 64);
            }
            if (lane == 0) {
                ring[tt & 7][m0]     = a0 + bl[m0];
                ring[tt & 7][m0 + 1] = a1 + bl[m0 + 1];
                ring[tt & 7][m0 + 2] = a2 + bl[m0 + 2];
                ring[tt & 7][m0 + 3] = a3 + bl[m0 + 3];
            }
        }
        if (idx1 <= 513) xbuf[idx1 & 1][tid] = xnext;
        tok_cur = tok_nxt;
        // no inter-block barrier: data arrival is the sync
    }
}

// ---------------------------------------------------------------------------
extern "C" void kernel_launch(void* const* d_in, const int* in_sizes, int n_in,
                              void* d_out, int out_size, void* d_ws, size_t ws_size,
                              hipStream_t stream) {
    const int*   in_seq   = (const int*)d_in[0];
    const int*   out_seq  = (const int*)d_in[1];
    const float* embed    = (const float*)d_in[2];
    const float* eos      = (const float*)d_in[3];
    const float* in_Wih   = (const float*)d_in[4];
    const float* in_Whh   = (const float*)d_in[5];
    const float* in_b     = (const float*)d_in[6];
    const float* out_Wih  = (const float*)d_in[7];
    const float* out_Whh  = (const float*)d_in[8];
    const float* out_b    = (const float*)d_in[9];
    const float* pg_Wih   = (const float*)d_in[10];
    const float* pg_Whh   = (const float*)d_in[11];
    const float* pg_b     = (const float*)d_in[12];

    u32* hseqB = (u32*)d_ws;                           // 524*1024 u32 (bf16 x2)

    // bf16 NaN sentinel 0xFFFF; fresh region per step -> no reuse races
    hipMemsetAsync(hseqB, 0xFF, (size_t)524 * 1024 * sizeof(u32), stream);

    float* out = (float*)d_out;
    void* args[] = { (void*)&in_Whh, (void*)&out_Whh, (void*)&pg_Wih, (void*)&pg_Whh,
                     (void*)&pg_b,
                     (void*)&in_Wih, (void*)&out_Wih, (void*)&in_b, (void*)&out_b,
                     (void*)&embed, (void*)&eos, (void*)&in_seq, (void*)&out_seq,
                     (void*)&hseqB, (void*)&out };
    hipLaunchCooperativeKernel((const void*)rnn_coop, dim3(NBLK), dim3(512),
                               args, 0, stream);
}